// Round 2
// baseline (60.560 us; speedup 1.0000x reference)
//
#include <hip/hip_runtime.h>
#include <hip/hip_cooperative_groups.h>

namespace cg = cooperative_groups;

#define SS 32
#define BB 128
#define VV 32000
#define EOS_ID 2
#define MAXK 128   // max candidates per row (mean ~20; huge safety margin)

// One block per batch row b:
//   Phase 1: scan targets[b,:] (32000 f32, float4-vectorized), compact label
//            indices into LDS via LDS atomics (order-invariant downstream).
//   Phase 2: gather G[t][k] = out[t,b,idx[k]] into LDS (scattered, parallel).
//   Phase 3: wave 0 runs the 32-step greedy argmax loop from LDS -> sums[b].
//   grid.sync(); block 0 reduces 128 sums (fixed double tree) -> d_out.
__global__ __launch_bounds__(1024) void ofl_fused(const float* __restrict__ out,
                                                  const float* __restrict__ tg,
                                                  float* __restrict__ sums,
                                                  float* __restrict__ outp) {
    __shared__ float G[SS][MAXK];   // 16 KiB; slot n holds EOS value
    __shared__ int sidx[MAXK];
    __shared__ int scnt;
    int b = blockIdx.x;
    int tid = threadIdx.x;
    if (tid == 0) scnt = 0;
    __syncthreads();

    // ---- Phase 1: compact ----
    const float4* t4 = reinterpret_cast<const float4*>(tg + (size_t)b * VV);
    for (int j = tid; j < VV / 4; j += 1024) {
        float4 v = t4[j];
        if (v.x > 0.5f) { int s = atomicAdd(&scnt, 1); if (s < MAXK - 1) sidx[s] = j * 4;     }
        if (v.y > 0.5f) { int s = atomicAdd(&scnt, 1); if (s < MAXK - 1) sidx[s] = j * 4 + 1; }
        if (v.z > 0.5f) { int s = atomicAdd(&scnt, 1); if (s < MAXK - 1) sidx[s] = j * 4 + 2; }
        if (v.w > 0.5f) { int s = atomicAdd(&scnt, 1); if (s < MAXK - 1) sidx[s] = j * 4 + 3; }
    }
    __syncthreads();
    int n = scnt;
    if (n > MAXK - 1) n = MAXK - 1;

    // ---- Phase 2: gather ----
    int tot = SS * (n + 1);
    for (int j = tid; j < tot; j += 1024) {
        int t = j / (n + 1);
        int k = j - t * (n + 1);
        int v = (k < n) ? sidx[k] : EOS_ID;
        G[t][k] = out[((size_t)t * BB + b) * VV + v];
    }
    __syncthreads();

    // ---- Phase 3: greedy selection (wave 0 only) ----
    if (tid < 64) {
        int lane = tid;
        bool alive0 = lane < n;
        bool alive1 = (lane + 64) < n;
        int remaining = n;
        float acc = 0.f;
        for (int t = 0; t < SS; ++t) {
            float cv;
            if (remaining > 0) {
                float v0 = alive0 ? G[t][lane]      : -INFINITY;
                int   i0 = alive0 ? sidx[lane]      : 0x7fffffff;
                float v1 = alive1 ? G[t][lane + 64] : -INFINITY;
                int   i1 = alive1 ? sidx[lane + 64] : 0x7fffffff;
                float val; int vidx, pos;
                if (v1 > v0 || (v1 == v0 && i1 < i0)) { val = v1; vidx = i1; pos = lane + 64; }
                else                                   { val = v0; vidx = i0; pos = lane; }
                for (int m = 1; m < 64; m <<= 1) {
                    float oval  = __shfl_xor(val,  m, 64);
                    int   ovidx = __shfl_xor(vidx, m, 64);
                    int   opos  = __shfl_xor(pos,  m, 64);
                    if (oval > val || (oval == val && ovidx < vidx)) {
                        val = oval; vidx = ovidx; pos = opos;
                    }
                }
                if (pos == lane)      alive0 = false;
                if (pos == lane + 64) alive1 = false;
                remaining--;
                cv = val;
            } else {
                cv = G[t][n];  // set exhausted -> EOS forever
            }
            acc += cv;
        }
        if (lane == 0) {
            sums[b] = acc;
            __threadfence();  // make sums[b] device-visible before grid sync
        }
    }

    cg::this_grid().sync();

    // ---- Finalize: block 0, wave 0, fixed-order double tree reduction ----
    if (b == 0 && tid < 64) {
        double s = (double)sums[tid] + (double)sums[tid + 64];
        for (int m = 1; m < 64; m <<= 1) s += __shfl_xor(s, m, 64);
        if (tid == 0) outp[0] = (float)(-s / (double)(SS * BB));
    }
}

extern "C" void kernel_launch(void* const* d_in, const int* in_sizes, int n_in,
                              void* d_out, int out_size, void* d_ws, size_t ws_size,
                              hipStream_t stream) {
    const float* outputs = (const float*)d_in[0];   // [S,B,V] fp32 log-probs
    // d_in[1] = output_symbols (unused in executed branch)
    const float* targets = (const float*)d_in[2];   // [B,V] fp32 multi-hot

    float* sums = (float*)d_ws;   // 128 floats
    float* outp = (float*)d_out;

    void* args[] = { (void*)&outputs, (void*)&targets, (void*)&sums, (void*)&outp };
    hipLaunchCooperativeKernel(reinterpret_cast<void*>(ofl_fused),
                               dim3(BB), dim3(1024), args, 0, stream);
}

// Round 3
// 35.712 us; speedup vs baseline: 1.6958x; 1.6958x over previous
//
#include <hip/hip_runtime.h>

#define SS 32
#define BB 128
#define VV 32000
#define EOS_ID 2
#define MAXK 128   // max candidates per row (mean ~20; huge safety margin)

// Kernel 1 — one block per batch row b:
//   Phase 1: scan targets[b,:] (32000 f32, float4), compact label indices
//            into LDS via LDS atomics (order-invariant downstream: greedy
//            tie-breaks on vocab index, not list position).
//   Phase 2: gather G[t][k] = out[t,b,idx[k]] into LDS (parallel scattered).
//   Phase 3: wave 0 runs the 32-step greedy argmax loop from LDS -> sums[b].
__global__ __launch_bounds__(1024) void ofl_rows(const float* __restrict__ out,
                                                 const float* __restrict__ tg,
                                                 float* __restrict__ sums) {
    __shared__ float G[SS][MAXK];   // 16 KiB; slot n holds EOS value
    __shared__ int sidx[MAXK];
    __shared__ int scnt;
    int b = blockIdx.x;
    int tid = threadIdx.x;
    if (tid == 0) scnt = 0;
    __syncthreads();

    // ---- Phase 1: compact ----
    const float4* t4 = reinterpret_cast<const float4*>(tg + (size_t)b * VV);
    for (int j = tid; j < VV / 4; j += 1024) {
        float4 v = t4[j];
        if (v.x > 0.5f) { int s = atomicAdd(&scnt, 1); if (s < MAXK - 1) sidx[s] = j * 4;     }
        if (v.y > 0.5f) { int s = atomicAdd(&scnt, 1); if (s < MAXK - 1) sidx[s] = j * 4 + 1; }
        if (v.z > 0.5f) { int s = atomicAdd(&scnt, 1); if (s < MAXK - 1) sidx[s] = j * 4 + 2; }
        if (v.w > 0.5f) { int s = atomicAdd(&scnt, 1); if (s < MAXK - 1) sidx[s] = j * 4 + 3; }
    }
    __syncthreads();
    int n = scnt;
    if (n > MAXK - 1) n = MAXK - 1;

    // ---- Phase 2: gather ----
    int tot = SS * (n + 1);
    for (int j = tid; j < tot; j += 1024) {
        int t = j / (n + 1);
        int k = j - t * (n + 1);
        int v = (k < n) ? sidx[k] : EOS_ID;
        G[t][k] = out[((size_t)t * BB + b) * VV + v];
    }
    __syncthreads();

    // ---- Phase 3: greedy selection (wave 0 only) ----
    if (tid < 64) {
        int lane = tid;
        bool alive0 = lane < n;
        bool alive1 = (lane + 64) < n;
        int remaining = n;
        float acc = 0.f;
        for (int t = 0; t < SS; ++t) {
            float cv;
            if (remaining > 0) {
                float v0 = alive0 ? G[t][lane]      : -INFINITY;
                int   i0 = alive0 ? sidx[lane]      : 0x7fffffff;
                float v1 = alive1 ? G[t][lane + 64] : -INFINITY;
                int   i1 = alive1 ? sidx[lane + 64] : 0x7fffffff;
                float val; int vidx, pos;
                if (v1 > v0 || (v1 == v0 && i1 < i0)) { val = v1; vidx = i1; pos = lane + 64; }
                else                                   { val = v0; vidx = i0; pos = lane; }
                for (int m = 1; m < 64; m <<= 1) {
                    float oval  = __shfl_xor(val,  m, 64);
                    int   ovidx = __shfl_xor(vidx, m, 64);
                    int   opos  = __shfl_xor(pos,  m, 64);
                    if (oval > val || (oval == val && ovidx < vidx)) {
                        val = oval; vidx = ovidx; pos = opos;
                    }
                }
                if (pos == lane)      alive0 = false;
                if (pos == lane + 64) alive1 = false;
                remaining--;
                cv = val;
            } else {
                cv = G[t][n];  // set exhausted -> EOS forever
            }
            acc += cv;
        }
        if (lane == 0) sums[b] = acc;
    }
}

// Kernel 2 — deterministic fixed-order reduction of 128 row sums.
__global__ __launch_bounds__(64) void ofl_finalize(const float* __restrict__ sums,
                                                   float* __restrict__ outp) {
    int lane = threadIdx.x;
    double s = (double)sums[lane] + (double)sums[lane + 64];
    for (int m = 1; m < 64; m <<= 1) s += __shfl_xor(s, m, 64);
    if (lane == 0) outp[0] = (float)(-s / (double)(SS * BB));
}

extern "C" void kernel_launch(void* const* d_in, const int* in_sizes, int n_in,
                              void* d_out, int out_size, void* d_ws, size_t ws_size,
                              hipStream_t stream) {
    const float* outputs = (const float*)d_in[0];   // [S,B,V] fp32 log-probs
    // d_in[1] = output_symbols (unused in executed branch)
    const float* targets = (const float*)d_in[2];   // [B,V] fp32 multi-hot

    float* sums = (float*)d_ws;   // 128 floats, written every call before read

    ofl_rows<<<dim3(BB), dim3(1024), 0, stream>>>(outputs, targets, sums);
    ofl_finalize<<<dim3(1), dim3(64), 0, stream>>>(sums, (float*)d_out);
}